// Round 12
// baseline (411.969 us; speedup 1.0000x reference)
//
#include <hip/hip_runtime.h>
#include <hip/hip_bf16.h>

#define N_NODES 1048576
#define H 128
#define B_SESS 4096
#define TILE 64

typedef __attribute__((ext_vector_type(8))) short bf16x8;
typedef __attribute__((ext_vector_type(4))) short bf16x4;
typedef __attribute__((ext_vector_type(4))) float f32x4;

__device__ inline short bc(float f) {
  return (short)__builtin_bit_cast(unsigned short, __float2bfloat16(f));
}

// ---------------------------------------------------------------- kernel 1
// fused prep: last-index scan + s_g zero + W2 f32->bf16
__global__ void k_prep(const int* __restrict__ batch, int* __restrict__ last_idx,
                       const float* __restrict__ W2, unsigned short* __restrict__ W2b,
                       float* __restrict__ s_g) {
  int i = blockIdx.x * 256 + threadIdx.x;
  if (i < N_NODES) {
    if (i == N_NODES - 1 || batch[i] != batch[i + 1]) last_idx[batch[i]] = i;
  }
  if (i < B_SESS * H) s_g[i] = 0.f;
  if (i < 4096) {
    float4 v = *reinterpret_cast<const float4*>(W2 + (size_t)i * 4);
    bf16x4 o;
    o[0] = bc(v.x); o[1] = bc(v.y); o[2] = bc(v.z); o[3] = bc(v.w);
    *reinterpret_cast<bf16x4*>(W2b + (size_t)i * 4) = o;
  }
}

// ---------------------------------------------------------------- kernel 2
// A_pre[b,h] = v_n[b] . W1[h,:] + b1[h] + b2[h]   (16 sessions/block)
__global__ void k_apre(const float* __restrict__ x, const int* __restrict__ last_idx,
                       const float* __restrict__ W1, const float* __restrict__ b1,
                       const float* __restrict__ b2, float* __restrict__ A_pre) {
  __shared__ float Wl[128][132];
  __shared__ float vn[16][128];
  int t = threadIdx.x;
  for (int i = 0; i < 16; ++i) {
    int e = (t + i * 256) * 4;
    int r = e >> 7, c = e & 127;
    float4 v = *reinterpret_cast<const float4*>(W1 + e);
    Wl[r][c] = v.x; Wl[r][c + 1] = v.y; Wl[r][c + 2] = v.z; Wl[r][c + 3] = v.w;
  }
  int b0 = blockIdx.x * 16;
  for (int i = t; i < 16 * 128; i += 256) {
    int s = i >> 7, c = i & 127;
    vn[s][c] = x[(size_t)last_idx[b0 + s] * H + c];
  }
  __syncthreads();
  int h = t & 127, si = t >> 7;
  float bias = b1[h] + b2[h];
  for (int s = si; s < 16; s += 2) {
    float acc = bias;
    #pragma unroll
    for (int k = 0; k < 128; k += 4) {
      float4 w = *reinterpret_cast<const float4*>(&Wl[h][k]);
      acc += vn[s][k] * w.x + vn[s][k + 1] * w.y + vn[s][k + 2] * w.z + vn[s][k + 3] * w.w;
    }
    A_pre[(size_t)(b0 + s) * H + h] = acc;
  }
}

// ---------------------------------------------------------------- kernel 3
// R6 structure (validated best): z = A_pre[batch] + x@W2^T (bf16 MFMA, K-split
// W2 staging 18.4KB), alpha = sigmoid(z).Wq + bq, s_g[b] += alpha * x.
// apre_s fast path; phase-2 as float4 (8 loads/thread), prefetched before the
// alph barrier.  LDS ~27.7KB, launch_bounds(256,5) -> 5 blocks/CU.
__global__ __launch_bounds__(256, 5)
void k_main(const float* __restrict__ x, const int* __restrict__ batch,
            const unsigned short* __restrict__ W2b, const float* __restrict__ Wq,
            const float* __restrict__ bq, const float* __restrict__ A_pre,
            float* __restrict__ s_g) {
  __shared__ unsigned short Wl[128][72];   // one K-half of W2 (144B rows)
  __shared__ float apre_s[16][128];        // staged A_pre rows (fast path)
  __shared__ float alph[TILE];
  __shared__ int bsegs[TILE + 1];
  __shared__ float wqs[128];
  int t = threadIdx.x;
  int node0 = blockIdx.x * TILE;
  int w = t >> 6, lane = t & 63, r = lane & 15, ks = lane >> 4;

  // ---- issue W2 half0 + x A-frag loads up front
  bf16x8 w0[4];
  #pragma unroll
  for (int i = 0; i < 4; ++i) {
    int u = t + i * 256, row = u >> 3, c = (u & 7) * 8;
    w0[i] = *reinterpret_cast<const bf16x8*>(W2b + row * 128 + c);
  }
  float4 af[8];
  const float* xrow = x + (size_t)(node0 + w * 16 + r) * H;
  #pragma unroll
  for (int k = 0; k < 4; ++k) {
    af[2 * k]     = *reinterpret_cast<const float4*>(xrow + k * 32 + ks * 8);
    af[2 * k + 1] = *reinterpret_cast<const float4*>(xrow + k * 32 + ks * 8 + 4);
  }
  int smin = batch[node0];
  int smax = batch[node0 + TILE - 1];
  int cnt = smax - smin + 1;
  bool fast = (cnt <= 16);
  if (fast) {                              // stage spanned A_pre rows (contiguous)
    const float4* src = reinterpret_cast<const float4*>(A_pre + ((size_t)smin << 7));
    float4* dst = reinterpret_cast<float4*>(&apre_s[0][0]);
    for (int i = t; i < cnt * 32; i += 256) dst[i] = src[i];
  }
  if (t <= TILE) {
    int idx = node0 + t;
    bsegs[t] = (idx < N_NODES) ? batch[idx] : -1;
  }
  if (t < 128) wqs[t] = Wq[t];

  // write W2 half0 to LDS
  #pragma unroll
  for (int i = 0; i < 4; ++i) {
    int u = t + i * 256, row = u >> 3, c = (u & 7) * 8;
    *reinterpret_cast<bf16x8*>(&Wl[row][c]) = w0[i];
  }
  // convert A-frags to bf16 (af dies here)
  bf16x8 afr[4];
  #pragma unroll
  for (int kg = 0; kg < 4; ++kg) {
    const float* afp = reinterpret_cast<const float*>(af);
    bf16x8 v;
    #pragma unroll
    for (int c = 0; c < 8; ++c) v[c] = bc(afp[kg * 8 + c]);
    afr[kg] = v;
  }
  __syncthreads();                         // Wl half0 + apre_s + bsegs ready

  // issue W2 half1 loads (latency hides under MFMA half0)
  bf16x8 w1[4];
  #pragma unroll
  for (int i = 0; i < 4; ++i) {
    int u = t + i * 256, row = u >> 3, c = (u & 7) * 8;
    w1[i] = *reinterpret_cast<const bf16x8*>(W2b + row * 128 + 64 + c);
  }

  f32x4 acc[8];
  #pragma unroll
  for (int nt = 0; nt < 8; ++nt) acc[nt] = (f32x4){0.f, 0.f, 0.f, 0.f};
  #pragma unroll
  for (int kg = 0; kg < 2; ++kg) {
    #pragma unroll
    for (int nt = 0; nt < 8; ++nt) {
      bf16x8 b = *reinterpret_cast<const bf16x8*>(&Wl[nt * 16 + r][kg * 32 + ks * 8]);
      acc[nt] = __builtin_amdgcn_mfma_f32_16x16x32_bf16(afr[kg], b, acc[nt], 0, 0, 0);
    }
  }
  __syncthreads();                         // half0 consumed
  #pragma unroll
  for (int i = 0; i < 4; ++i) {
    int u = t + i * 256, row = u >> 3, c = (u & 7) * 8;
    *reinterpret_cast<bf16x8*>(&Wl[row][c]) = w1[i];
  }
  __syncthreads();                         // half1 ready
  #pragma unroll
  for (int kg = 2; kg < 4; ++kg) {
    #pragma unroll
    for (int nt = 0; nt < 8; ++nt) {
      bf16x8 b = *reinterpret_cast<const bf16x8*>(&Wl[nt * 16 + r][(kg - 2) * 32 + ks * 8]);
      acc[nt] = __builtin_amdgcn_mfma_f32_16x16x32_bf16(afr[kg], b, acc[nt], 0, 0, 0);
    }
  }

  // ---- alpha: sigmoid + Wq-dot + 16-lane reduce
  float bqv = bq[0];
  float pa[4];
#define DO_ALPHA(GET) do {                                                   \
    _Pragma("unroll")                                                        \
    for (int j = 0; j < 4; ++j) {                                            \
      int row = bsegs[w * 16 + ks * 4 + j];                                  \
      float s = 0.f;                                                         \
      _Pragma("unroll")                                                      \
      for (int nt = 0; nt < 8; ++nt) {                                       \
        int col = nt * 16 + r;                                               \
        float z = acc[nt][j] + (GET);                                        \
        float g = 1.0f / (1.0f + __expf(-z));                                \
        s += g * wqs[col];                                                   \
      }                                                                      \
      s += __shfl_xor(s, 1); s += __shfl_xor(s, 2);                          \
      s += __shfl_xor(s, 4); s += __shfl_xor(s, 8);                          \
      pa[j] = s + bqv;                                                       \
    } } while (0)
  if (fast) DO_ALPHA(apre_s[row - smin][col]);
  else      DO_ALPHA(A_pre[(size_t)row * H + col]);
#undef DO_ALPHA
  if (r == 0) {
    #pragma unroll
    for (int j = 0; j < 4; ++j) alph[w * 16 + ks * 4 + j] = pa[j];
  }

  // ---- issue phase-2 x loads (float4) before the alph barrier
  int col4 = t & 31;                       // h = col4*4 .. +3
  int ng = t >> 5;                         // node-octet [ng*8, ng*8+8)
  const float4* xp4 = reinterpret_cast<const float4*>(
      x + (size_t)(node0 + ng * 8) * H) + col4;
  float4 x4v[8];
  #pragma unroll
  for (int n = 0; n < 8; ++n) x4v[n] = xp4[n * 32];   // 32 float4 per row
  __syncthreads();                         // alph ready

  // ---- phase 2: s_g[seg, h..h+3] += alpha_i * x[i, h..h+3]
  float4 acc4 = {0.f, 0.f, 0.f, 0.f};
  #pragma unroll
  for (int n = 0; n < 8; ++n) {
    int ln = ng * 8 + n;
    float a = alph[ln];
    acc4.x += a * x4v[n].x;
    acc4.y += a * x4v[n].y;
    acc4.z += a * x4v[n].z;
    acc4.w += a * x4v[n].w;
    if (n == 7 || bsegs[ln] != bsegs[ln + 1]) {
      float* dst = s_g + ((size_t)bsegs[ln] << 7) + col4 * 4;
      atomicAdd(dst + 0, acc4.x);
      atomicAdd(dst + 1, acc4.y);
      atomicAdd(dst + 2, acc4.z);
      atomicAdd(dst + 3, acc4.w);
      acc4 = (float4){0.f, 0.f, 0.f, 0.f};
    }
  }
}

// ---------------------------------------------------------------- kernel 4
// s_h[b,h] = b3[h] + concat(v_n[b], s_g[b]) . W3[h,:]   (16 sessions/block)
__global__ void k_final(const float* __restrict__ x, const int* __restrict__ last_idx,
                        const float* __restrict__ s_g, const float* __restrict__ W3,
                        const float* __restrict__ b3, float* __restrict__ out) {
  __shared__ float Wl[128][132];
  __shared__ float vin[16][256];
  int t = threadIdx.x;
  int b0 = blockIdx.x * 16;
  for (int i = t; i < 16 * 256; i += 256) {
    int s = i >> 8, c = i & 255;
    float v;
    if (c < 128) v = x[(size_t)last_idx[b0 + s] * H + c];
    else         v = s_g[(size_t)(b0 + s) * H + (c - 128)];
    vin[s][c] = v;
  }
  int h = t & 127, si = t >> 7;
  float res[8];
  for (int half = 0; half < 2; ++half) {
    __syncthreads();
    for (int i = 0; i < 16; ++i) {
      int e = (t + i * 256) * 4;
      int r = e >> 7, c = e & 127;
      float4 v = *reinterpret_cast<const float4*>(W3 + (size_t)r * 256 + half * 128 + c);
      Wl[r][c] = v.x; Wl[r][c + 1] = v.y; Wl[r][c + 2] = v.z; Wl[r][c + 3] = v.w;
    }
    __syncthreads();
    #pragma unroll
    for (int sI = 0; sI < 8; ++sI) {
      int s = si + sI * 2;
      float acc = 0.f;
      #pragma unroll
      for (int k = 0; k < 128; k += 4) {
        float4 wv = *reinterpret_cast<const float4*>(&Wl[h][k]);
        acc += vin[s][half * 128 + k] * wv.x + vin[s][half * 128 + k + 1] * wv.y +
               vin[s][half * 128 + k + 2] * wv.z + vin[s][half * 128 + k + 3] * wv.w;
      }
      if (half == 0) res[sI] = acc;
      else out[(size_t)(b0 + s) * H + h] = res[sI] + acc + b3[h];
    }
  }
}

// ----------------------------------------------------------------
extern "C" void kernel_launch(void* const* d_in, const int* in_sizes, int n_in,
                              void* d_out, int out_size, void* d_ws, size_t ws_size,
                              hipStream_t stream) {
  const float* x     = (const float*)d_in[0];
  const int*   batch = (const int*)d_in[1];
  const float* W1    = (const float*)d_in[2];
  const float* b1    = (const float*)d_in[3];
  const float* W2    = (const float*)d_in[4];
  const float* b2    = (const float*)d_in[5];
  const float* Wq    = (const float*)d_in[6];
  const float* bq    = (const float*)d_in[7];
  const float* W3    = (const float*)d_in[8];
  const float* b3    = (const float*)d_in[9];
  float* out = (float*)d_out;

  char* ws = (char*)d_ws;
  int*            last_idx = (int*)ws;                                    // 16 KB
  float*          A_pre    = (float*)(ws + 16384);                        // 2 MB
  float*          s_g      = (float*)(ws + 16384 + 2097152);              // 2 MB
  unsigned short* W2b      = (unsigned short*)(ws + 16384 + 2 * 2097152); // 32 KB

  k_prep<<<N_NODES / 256, 256, 0, stream>>>(batch, last_idx, W2, W2b, s_g);
  k_apre<<<B_SESS / 16, 256, 0, stream>>>(x, last_idx, W1, b1, b2, A_pre);
  k_main<<<N_NODES / TILE, 256, 0, stream>>>(x, batch, W2b, Wq, bq, A_pre, s_g);
  k_final<<<B_SESS / 16, 256, 0, stream>>>(x, last_idx, s_g, W3, b3, out);
}

// Round 13
// 220.902 us; speedup vs baseline: 1.8649x; 1.8649x over previous
//
#include <hip/hip_runtime.h>
#include <hip/hip_bf16.h>

#define N_NODES 1048576
#define H 128
#define B_SESS 4096
#define TILE 64

typedef __attribute__((ext_vector_type(8))) short bf16x8;
typedef __attribute__((ext_vector_type(4))) short bf16x4;
typedef __attribute__((ext_vector_type(4))) float f32x4;

__device__ inline short bc(float f) {
  return (short)__builtin_bit_cast(unsigned short, __float2bfloat16(f));
}

// ---------------------------------------------------------------- kernel 1
// fused prep: last-index scan + s_g zero + W2 f32->bf16 PRE-SWIZZLED
// (16B unit u of row goes to unit u ^ (row&7); involution, matches k_main)
__global__ void k_prep(const int* __restrict__ batch, int* __restrict__ last_idx,
                       const float* __restrict__ W2, unsigned short* __restrict__ W2s,
                       float* __restrict__ s_g) {
  int i = blockIdx.x * 256 + threadIdx.x;
  if (i < N_NODES) {
    if (i == N_NODES - 1 || batch[i] != batch[i + 1]) last_idx[batch[i]] = i;
  }
  if (i < B_SESS * H) s_g[i] = 0.f;
  if (i < 2048) {                          // 128 rows x 16 units of 8 bf16
    int row = i >> 4, u = i & 15;
    const float* src = W2 + row * 128 + u * 8;
    float4 a = *reinterpret_cast<const float4*>(src);
    float4 b = *reinterpret_cast<const float4*>(src + 4);
    bf16x8 o;
    o[0] = bc(a.x); o[1] = bc(a.y); o[2] = bc(a.z); o[3] = bc(a.w);
    o[4] = bc(b.x); o[5] = bc(b.y); o[6] = bc(b.z); o[7] = bc(b.w);
    int up = u ^ (row & 7);
    *reinterpret_cast<bf16x8*>(W2s + row * 128 + up * 8) = o;
  }
}

// ---------------------------------------------------------------- kernel 2
// A_pre[b,h] = v_n[b] . W1[h,:] + b1[h] + b2[h]
__global__ void k_apre(const float* __restrict__ x, const int* __restrict__ last_idx,
                       const float* __restrict__ W1, const float* __restrict__ b1,
                       const float* __restrict__ b2, float* __restrict__ A_pre) {
  __shared__ float Wl[128][132];
  __shared__ float vn[8][128];
  int t = threadIdx.x;
  for (int i = 0; i < 16; ++i) {
    int e = (t + i * 256) * 4;
    int r = e >> 7, c = e & 127;
    float4 v = *reinterpret_cast<const float4*>(W1 + e);
    Wl[r][c] = v.x; Wl[r][c + 1] = v.y; Wl[r][c + 2] = v.z; Wl[r][c + 3] = v.w;
  }
  int b0 = blockIdx.x * 8;
  for (int i = t; i < 8 * 128; i += 256) {
    int s = i >> 7, c = i & 127;
    vn[s][c] = x[(size_t)last_idx[b0 + s] * H + c];
  }
  __syncthreads();
  int h = t & 127, si = t >> 7;
  float bias = b1[h] + b2[h];
  for (int s = si; s < 8; s += 2) {
    float acc = bias;
    #pragma unroll
    for (int k = 0; k < 128; k += 4) {
      float4 w = *reinterpret_cast<const float4*>(&Wl[h][k]);
      acc += vn[s][k] * w.x + vn[s][k + 1] * w.y + vn[s][k + 2] * w.z + vn[s][k + 3] * w.w;
    }
    A_pre[(size_t)(b0 + s) * H + h] = acc;
  }
}

// ---------------------------------------------------------------- kernel 3
// R6 skeleton, spill-free: W2 (pre-swizzled bf16) staged via async
// global_load_lds (no VGPR round-trip, 2 barriers total), MFMA z-tiles,
// alpha = sigmoid(z).Wq + bq, s_g[b] += alpha * x.
__global__ __launch_bounds__(256, 4)
void k_main(const float* __restrict__ x, const int* __restrict__ batch,
            const unsigned short* __restrict__ W2s, const float* __restrict__ Wq,
            const float* __restrict__ bq, const float* __restrict__ A_pre,
            float* __restrict__ s_g) {
  __shared__ unsigned short Wl[128][128];  // swizzled bf16 W2 (32 KB, linear copy)
  __shared__ float apre_s[8][128];         // staged A_pre rows (fast path, 4 KB)
  __shared__ float alph[TILE];
  __shared__ int bsegs[TILE + 1];
  __shared__ float wqs[128];
  int t = threadIdx.x;
  int node0 = blockIdx.x * TILE;
  int w = t >> 6, lane = t & 63, r = lane & 15, ks = lane >> 4;

  // ---- async W2 -> LDS: 32 x 1KB chunks, linear (pre-swizzled in global)
  #pragma unroll
  for (int i = 0; i < 8; ++i) {
    int seg = w * 8 + i;
    __builtin_amdgcn_global_load_lds(
        reinterpret_cast<const unsigned int*>(
            reinterpret_cast<const char*>(W2s) + seg * 1024 + lane * 16),
        reinterpret_cast<unsigned int*>(
            reinterpret_cast<char*>(&Wl[0][0]) + seg * 1024),
        16, 0, 0);
  }

  // ---- x A-frag loads (paired float4: full 64B-line use per row)
  float4 af[8];
  const float* xrow = x + (size_t)(node0 + w * 16 + r) * H;
  #pragma unroll
  for (int k = 0; k < 4; ++k) {
    af[2 * k]     = *reinterpret_cast<const float4*>(xrow + k * 32 + ks * 8);
    af[2 * k + 1] = *reinterpret_cast<const float4*>(xrow + k * 32 + ks * 8 + 4);
  }
  int smin = batch[node0];
  int smax = batch[node0 + TILE - 1];
  int cnt = smax - smin + 1;
  bool fast = (cnt <= 8);
  if (fast) {                              // stage spanned A_pre rows (contiguous)
    const float4* src = reinterpret_cast<const float4*>(A_pre + ((size_t)smin << 7));
    float4* dst = reinterpret_cast<float4*>(&apre_s[0][0]);
    for (int i = t; i < cnt * 32; i += 256) dst[i] = src[i];
  }
  if (t <= TILE) {
    int idx = node0 + t;
    bsegs[t] = (idx < N_NODES) ? batch[idx] : -1;
  }
  if (t < 128) wqs[t] = Wq[t];

  // convert A-frags to bf16 (af dies here)
  bf16x8 afr[4];
  #pragma unroll
  for (int kg = 0; kg < 4; ++kg) {
    const float* afp = reinterpret_cast<const float*>(af);
    bf16x8 v;
    #pragma unroll
    for (int c = 0; c < 8; ++c) v[c] = bc(afp[kg * 8 + c]);
    afr[kg] = v;
  }
  __syncthreads();                         // drains global_load_lds + ds writes

  // ---- MFMA: z partials (C layout: row = ks*4+j, col = nt*16+r)
  int sw = r & 7;                          // row&7 == r&7 for row = nt*16+r
  f32x4 acc[8];
  #pragma unroll
  for (int nt = 0; nt < 8; ++nt) acc[nt] = (f32x4){0.f, 0.f, 0.f, 0.f};
  #pragma unroll
  for (int kg = 0; kg < 4; ++kg) {
    int up = (kg * 4 + ks) ^ sw;           // un-swizzle on read
    #pragma unroll
    for (int nt = 0; nt < 8; ++nt) {
      bf16x8 b = *reinterpret_cast<const bf16x8*>(&Wl[nt * 16 + r][up * 8]);
      acc[nt] = __builtin_amdgcn_mfma_f32_16x16x32_bf16(afr[kg], b, acc[nt], 0, 0, 0);
    }
  }

  // ---- alpha: sigmoid + Wq-dot + 16-lane reduce
  float bqv = bq[0];
  float pa[4];
#define DO_ALPHA(GET) do {                                                   \
    _Pragma("unroll")                                                        \
    for (int j = 0; j < 4; ++j) {                                            \
      int row = bsegs[w * 16 + ks * 4 + j];                                  \
      float s = 0.f;                                                         \
      _Pragma("unroll")                                                      \
      for (int nt = 0; nt < 8; ++nt) {                                       \
        int col = nt * 16 + r;                                               \
        float z = acc[nt][j] + (GET);                                        \
        float g = 1.0f / (1.0f + __expf(-z));                                \
        s += g * wqs[col];                                                   \
      }                                                                      \
      s += __shfl_xor(s, 1); s += __shfl_xor(s, 2);                          \
      s += __shfl_xor(s, 4); s += __shfl_xor(s, 8);                          \
      pa[j] = s + bqv;                                                       \
    } } while (0)
  if (fast) DO_ALPHA(apre_s[row - smin][col]);
  else      DO_ALPHA(A_pre[(size_t)row * H + col]);
#undef DO_ALPHA
  if (r == 0) {
    #pragma unroll
    for (int j = 0; j < 4; ++j) alph[w * 16 + ks * 4 + j] = pa[j];
  }

  // ---- issue phase-2 x loads before the alph barrier (latency hidden)
  int h = t & 127, grp = t >> 7;           // 2 groups x 32 nodes
  int base = grp * 32;
  const float* xp = x + (size_t)(node0 + base) * H + h;
  float xv[32];
  #pragma unroll
  for (int n = 0; n < 32; ++n) xv[n] = xp[(size_t)n * H];
  __syncthreads();                         // alph ready

  // ---- phase 2: s_g[b,h] += alpha_i * x[i,h]
  float accum = 0.f;
  #pragma unroll
  for (int n = 0; n < 32; ++n) {
    int ln = base + n;
    accum += alph[ln] * xv[n];
    if (bsegs[ln] != bsegs[ln + 1]) {
      atomicAdd(&s_g[((size_t)bsegs[ln] << 7) + h], accum);
      accum = 0.f;
    }
  }
  if (accum != 0.f) atomicAdd(&s_g[((size_t)bsegs[base + 31] << 7) + h], accum);
}

// ---------------------------------------------------------------- kernel 4
// s_h[b,h] = b3[h] + concat(v_n[b], s_g[b]) . W3[h,:]
__global__ void k_final(const float* __restrict__ x, const int* __restrict__ last_idx,
                        const float* __restrict__ s_g, const float* __restrict__ W3,
                        const float* __restrict__ b3, float* __restrict__ out) {
  __shared__ float Wl[128][132];
  __shared__ float vin[8][256];
  int t = threadIdx.x;
  int b0 = blockIdx.x * 8;
  for (int i = t; i < 8 * 256; i += 256) {
    int s = i >> 8, c = i & 255;
    float v;
    if (c < 128) v = x[(size_t)last_idx[b0 + s] * H + c];
    else         v = s_g[(size_t)(b0 + s) * H + (c - 128)];
    vin[s][c] = v;
  }
  int h = t & 127, si = t >> 7;
  float res[4];
  for (int half = 0; half < 2; ++half) {
    __syncthreads();
    for (int i = 0; i < 16; ++i) {
      int e = (t + i * 256) * 4;
      int r = e >> 7, c = e & 127;
      float4 v = *reinterpret_cast<const float4*>(W3 + (size_t)r * 256 + half * 128 + c);
      Wl[r][c] = v.x; Wl[r][c + 1] = v.y; Wl[r][c + 2] = v.z; Wl[r][c + 3] = v.w;
    }
    __syncthreads();
    #pragma unroll
    for (int sI = 0; sI < 4; ++sI) {
      int s = si + sI * 2;
      float acc = 0.f;
      #pragma unroll
      for (int k = 0; k < 128; k += 4) {
        float4 wv = *reinterpret_cast<const float4*>(&Wl[h][k]);
        acc += vin[s][half * 128 + k] * wv.x + vin[s][half * 128 + k + 1] * wv.y +
               vin[s][half * 128 + k + 2] * wv.z + vin[s][half * 128 + k + 3] * wv.w;
      }
      if (half == 0) res[sI] = acc;
      else out[(size_t)(b0 + s) * H + h] = res[sI] + acc + b3[h];
    }
  }
}

// ----------------------------------------------------------------
extern "C" void kernel_launch(void* const* d_in, const int* in_sizes, int n_in,
                              void* d_out, int out_size, void* d_ws, size_t ws_size,
                              hipStream_t stream) {
  const float* x     = (const float*)d_in[0];
  const int*   batch = (const int*)d_in[1];
  const float* W1    = (const float*)d_in[2];
  const float* b1    = (const float*)d_in[3];
  const float* W2    = (const float*)d_in[4];
  const float* b2    = (const float*)d_in[5];
  const float* Wq    = (const float*)d_in[6];
  const float* bq    = (const float*)d_in[7];
  const float* W3    = (const float*)d_in[8];
  const float* b3    = (const float*)d_in[9];
  float* out = (float*)d_out;

  char* ws = (char*)d_ws;
  int*            last_idx = (int*)ws;                                    // 16 KB
  float*          A_pre    = (float*)(ws + 16384);                        // 2 MB
  float*          s_g      = (float*)(ws + 16384 + 2097152);              // 2 MB
  unsigned short* W2s      = (unsigned short*)(ws + 16384 + 2 * 2097152); // 32 KB

  k_prep<<<N_NODES / 256, 256, 0, stream>>>(batch, last_idx, W2, W2s, s_g);
  k_apre<<<B_SESS / 8, 256, 0, stream>>>(x, last_idx, W1, b1, b2, A_pre);
  k_main<<<N_NODES / TILE, 256, 0, stream>>>(x, batch, W2s, Wq, bq, A_pre, s_g);
  k_final<<<B_SESS / 8, 256, 0, stream>>>(x, last_idx, s_g, W3, b3, out);
}